// Round 5
// baseline (723.957 us; speedup 1.0000x reference)
//
#include <hip/hip_runtime.h>
#include <hip/hip_bf16.h>

#define B_ 128
#define F_ 100
#define N_ 512
#define H_ 1024
#define P_ 512
#define E_ 8
#define TR_ 112          // act rows stored per trial (7 frags x 16)
#define BK 64

typedef __attribute__((ext_vector_type(8))) short bf16x8;
typedef __attribute__((ext_vector_type(4))) float f32x4;

// async global->LDS DMA, 16B/lane, LDS dest = wave-uniform base + lane*16
#define GLOAD16(g, l) __builtin_amdgcn_global_load_lds(                      \
    (const __attribute__((address_space(1))) void*)(g),                      \
    (__attribute__((address_space(3))) void*)(l), 16, 0, 0)

static __device__ __forceinline__ short f2bf(float f) {
    __hip_bfloat16 h = __float2bfloat16(f);
    short s;
    __builtin_memcpy(&s, &h, sizeof(s));
    return s;
}

// ONE prep kernel, grid sections:
//   [0,3200)      convert x [B][F][N] fp32 -> xbf [12800][N] bf16 (linear, no perm)
//   [3200,4224)   transpose W1 [E][512][1024] -> W1T [E][1024][512] bf16
//   [4224,5248)   transpose W2 [E][1024][512] -> W2T [E][512][1024] bf16
//   5248          sort TILE TABLE by expert (data stays in trial order):
//                 ttab[slot]=(trial,eid); GEMM slot s -> XCD s/16 owns 16
//                 expert-contiguous trials -> per-XCD L2 holds 1-2 experts.
__global__ __launch_bounds__(256) void prep(
    const float* __restrict__ x, const float* __restrict__ W1,
    const float* __restrict__ W2, const int* __restrict__ eid,
    short* __restrict__ xbf, short* __restrict__ W1T, short* __restrict__ W2T,
    int2* __restrict__ ttab) {
    __shared__ float tile[64][65];
    __shared__ int scnt[E_], sbase[E_];
    const int bx = blockIdx.x;
    const int t = threadIdx.x;
    if (bx < 3200) {  // ---- convert x ----
        const int g = bx * 256 + t;
        const int col = (g & 63) * 8;
        const int row = g >> 6;  // 0..12799
        const float* xp = x + (size_t)row * N_ + col;
        const float4 v0 = *(const float4*)(xp);
        const float4 v1 = *(const float4*)(xp + 4);
        union { short s[8]; uint4 u; } o;
        o.s[0] = f2bf(v0.x); o.s[1] = f2bf(v0.y);
        o.s[2] = f2bf(v0.z); o.s[3] = f2bf(v0.w);
        o.s[4] = f2bf(v1.x); o.s[5] = f2bf(v1.y);
        o.s[6] = f2bf(v1.z); o.s[7] = f2bf(v1.w);
        *(uint4*)(xbf + (size_t)row * N_ + col) = o.u;
    } else if (bx < 5248) {  // ---- weight transpose+convert ----
        const float* W; short* WT; int R, C, r0, c0, e;
        if (bx < 4224) {
            const int idx = bx - 3200;
            e = idx >> 7; const int i = idx & 127;
            W = W1; WT = W1T; R = N_; C = H_;
            r0 = (i >> 4) * 64; c0 = (i & 15) * 64;
        } else {
            const int idx = bx - 4224;
            e = idx >> 7; const int i = idx & 127;
            W = W2; WT = W2T; R = H_; C = P_;
            r0 = (i & 15) * 64; c0 = (i >> 4) * 64;
        }
        const float* Wp = W + (size_t)e * R * C;
        short* WTp = WT + (size_t)e * C * R;
        {
            const int c4 = (t & 15) * 4, r = t >> 4;
#pragma unroll
            for (int p = 0; p < 4; p++) {
                const int row = p * 16 + r;
                const float4 v = *(const float4*)(Wp + (size_t)(r0 + row) * C + c0 + c4);
                tile[row][c4 + 0] = v.x; tile[row][c4 + 1] = v.y;
                tile[row][c4 + 2] = v.z; tile[row][c4 + 3] = v.w;
            }
        }
        __syncthreads();
        {
            const int r8 = (t & 7) * 8, cl = t >> 3;
#pragma unroll
            for (int p = 0; p < 2; p++) {
                const int c = p * 32 + cl;
                union { short s[8]; uint4 u; } o;
#pragma unroll
                for (int j = 0; j < 8; j++) o.s[j] = f2bf(tile[r8 + j][c]);
                *(uint4*)(&WTp[(size_t)(c0 + c) * R + r0 + r8]) = o.u;
            }
        }
    } else {  // ---- tile-table sort (one block) ----
        if (t < E_) scnt[t] = 0;
        __syncthreads();
        int my_e = 0;
        if (t < B_) { my_e = eid[t]; atomicAdd(&scnt[my_e], 1); }
        __syncthreads();
        if (t == 0) {
            int s = 0;
            for (int i = 0; i < E_; i++) { sbase[i] = s; s += scnt[i]; }
        }
        __syncthreads();
        if (t < B_) {
            const int pos = atomicAdd(&sbase[my_e], 1);
            ttab[pos] = make_int2(t, my_e);
        }
    }
}

// 128(112 eff)x128 tile GEMM, one TRIAL per m-tile. BK=64, 4 waves 2x2
// (m-wave 0: 4 frags rows 0-63; m-wave 1: 3 frags rows 64-111), async
// global_load_lds staging, XOR-swizzled LDS (swizzle on GLOBAL address).
// Staged rows 100/112..127 are garbage (finite) and never stored.
// FIRST:  act[trial*112+row][col] = softsign(xbf @ W1T^T + b1), bf16
// !FIRST: out[trial][row<100][col] = act @ W2T^T + b2, fp32
template <int KDIM, bool FIRST>
__global__ __launch_bounds__(256, 4) void gemm_kernel(
    const short* __restrict__ A,     // FIRST: xbf [12800+pad][512]; else act [TR_*B_+pad][1024]
    const short* __restrict__ WT,    // [E][NCOLS][KDIM] bf16, K-contig
    const float* __restrict__ bias,  // [E][NCOLS]
    const int2* __restrict__ ttab,   // [B_] (trial, expert), expert-sorted
    short* __restrict__ actout,      // FIRST
    float* __restrict__ out)         // !FIRST
{
    constexpr int NCOLS = FIRST ? H_ : P_;
    __shared__ short sA[128 * BK];
    __shared__ short sB[128 * BK];
    const int slot = (blockIdx.x & 7) * 16 + (blockIdx.x >> 3);
    const int2 te = ttab[slot];
    const int trial = te.x, e = te.y;
    const int n0 = blockIdx.y * 128;
    const int t = threadIdx.x;
    const int lane = t & 63, w = t >> 6;
    const int wm = (w >> 1) * 64, wn = (w & 1) * 64;
    const int MI = (w >> 1) ? 3 : 4;   // wave-uniform
    const int l15 = lane & 15, quad = lane >> 4;
    const int lr = lane >> 3;                 // staging row 0..7
    const int lc = (((lane & 7) ^ lr) * 8);   // XOR-swizzled col chunk

    f32x4 acc[4][4];
#pragma unroll
    for (int mi = 0; mi < 4; mi++)
#pragma unroll
        for (int ni = 0; ni < 4; ni++)
            acc[mi][ni] = (f32x4)(0.0f);

    const short* Ap = A + (size_t)trial * (FIRST ? F_ : TR_) * KDIM;
    const short* Bp = WT + ((size_t)e * NCOLS + n0) * KDIM;

    for (int k0 = 0; k0 < KDIM; k0 += BK) {
#pragma unroll
        for (int i = 0; i < 4; i++) {
            const int rb = w * 32 + i * 8;
            GLOAD16(Ap + (size_t)(rb + lr) * KDIM + k0 + lc, &sA[rb * BK]);
        }
#pragma unroll
        for (int i = 0; i < 4; i++) {
            const int rb = w * 32 + i * 8;
            GLOAD16(Bp + (size_t)(rb + lr) * KDIM + k0 + lc, &sB[rb * BK]);
        }
        __syncthreads();
#pragma unroll
        for (int ks = 0; ks < 2; ks++) {
            // row&7 == l15&7 for all frags -> hoist the swizzle
            const int sw = (((ks * 4 + quad) ^ (l15 & 7)) * 8);
            bf16x8 af[4], bfr[4];
            for (int mi = 0; mi < MI; mi++)
                af[mi] = *(const bf16x8*)(&sA[(wm + mi * 16 + l15) * BK + sw]);
#pragma unroll
            for (int ni = 0; ni < 4; ni++)
                bfr[ni] = *(const bf16x8*)(&sB[(wn + ni * 16 + l15) * BK + sw]);
            for (int mi = 0; mi < MI; mi++)
#pragma unroll
                for (int ni = 0; ni < 4; ni++)
                    acc[mi][ni] = __builtin_amdgcn_mfma_f32_16x16x32_bf16(af[mi], bfr[ni], acc[mi][ni], 0, 0, 0);
        }
        __syncthreads();
    }

    // epilogue: C/D layout col=lane&15, row=quad*4+reg
    for (int mi = 0; mi < MI; mi++) {
#pragma unroll
        for (int ni = 0; ni < 4; ni++) {
            const int col = n0 + wn + ni * 16 + l15;
            const float bv = bias[(size_t)e * NCOLS + col];
#pragma unroll
            for (int r = 0; r < 4; r++) {
                const int row = wm + mi * 16 + quad * 4 + r;  // 0..111
                float v = acc[mi][ni][r] + bv;
                if constexpr (FIRST) {
                    v = v / (1.0f + fabsf(v));  // softsign, SCALE=1
                    actout[((size_t)trial * TR_ + row) * H_ + col] = f2bf(v);
                } else {
                    if (row < F_)
                        out[((size_t)trial * F_ + row) * P_ + col] = v;
                }
            }
        }
    }
}

extern "C" void kernel_launch(void* const* d_in, const int* in_sizes, int n_in,
                              void* d_out, int out_size, void* d_ws, size_t ws_size,
                              hipStream_t stream) {
    const float* x  = (const float*)d_in[0];
    const int* eid  = (const int*)d_in[1];
    const float* W1 = (const float*)d_in[2];
    const float* b1 = (const float*)d_in[3];
    const float* W2 = (const float*)d_in[4];
    const float* b2 = (const float*)d_in[5];
    float* out = (float*)d_out;

    char* ws = (char*)d_ws;
    short* W1T = (short*)(ws);                          // [E][H][N]        8 MiB
    short* W2T = (short*)(ws + (size_t)(8u << 20));     // [E][P][H]        8 MiB
    short* act = (short*)(ws + (size_t)(16u << 20));    // [128*112+pad][H] ~30 MiB
    short* xbf = (short*)(ws + (size_t)(47u << 20));    // [12800+pad][N]  ~14 MiB
    int2* ttab = (int2*)(ws + (size_t)(62u << 20));     // [B_]

    prep<<<dim3(5249), 256, 0, stream>>>(x, W1, W2, eid, xbf, W1T, W2T, ttab);
    gemm_kernel<N_, true><<<dim3(B_, H_ / 128), 256, 0, stream>>>(xbf, W1T, b1, ttab, act, nullptr);
    gemm_kernel<H_, false><<<dim3(B_, P_ / 128), 256, 0, stream>>>(act, W2T, b2, ttab, nullptr, out);
}

// Round 6
// 162.944 us; speedup vs baseline: 4.4430x; 4.4430x over previous
//
#include <hip/hip_runtime.h>
#include <hip/hip_bf16.h>

#define B_ 128
#define F_ 100
#define N_ 512
#define H_ 1024
#define P_ 512
#define E_ 8
#define BK 64

typedef __attribute__((ext_vector_type(8))) short bf16x8;
typedef __attribute__((ext_vector_type(4))) float f32x4;

// async global->LDS DMA, 16B/lane, LDS dest = wave-uniform base + lane*16
#define GLOAD16(g, l) __builtin_amdgcn_global_load_lds(                      \
    (const __attribute__((address_space(1))) void*)(g),                      \
    (__attribute__((address_space(3))) void*)(l), 16, 0, 0)

static __device__ __forceinline__ short f2bf(float f) {
    __hip_bfloat16 h = __float2bfloat16(f);
    short s;
    __builtin_memcpy(&s, &h, sizeof(s));
    return s;
}

// ONE prep kernel, grid sections:
//   [0,3200)      convert x [B][F][N] fp32 -> xbf [12800][N] bf16 (linear)
//   [3200,4224)   transpose W1 [E][512][1024] -> W1T [E][1024][512] bf16
//   [4224,5248)   transpose W2 [E][1024][512] -> W2T [E][512][1024] bf16
//   5248          tile table sorted by expert (data stays in trial order):
//                 ttab[slot]=(trial,eid); GEMM slot s -> XCD s%8-grouped so
//                 each XCD sees 16 expert-contiguous trials (1-2 experts).
__global__ __launch_bounds__(256) void prep(
    const float* __restrict__ x, const float* __restrict__ W1,
    const float* __restrict__ W2, const int* __restrict__ eid,
    short* __restrict__ xbf, short* __restrict__ W1T, short* __restrict__ W2T,
    int2* __restrict__ ttab) {
    __shared__ float tile[64][65];
    __shared__ int scnt[E_], sbase[E_];
    const int bx = blockIdx.x;
    const int t = threadIdx.x;
    if (bx < 3200) {  // ---- convert x ----
        const int g = bx * 256 + t;
        const int col = (g & 63) * 8;
        const int row = g >> 6;  // 0..12799
        const float* xp = x + (size_t)row * N_ + col;
        const float4 v0 = *(const float4*)(xp);
        const float4 v1 = *(const float4*)(xp + 4);
        union { short s[8]; uint4 u; } o;
        o.s[0] = f2bf(v0.x); o.s[1] = f2bf(v0.y);
        o.s[2] = f2bf(v0.z); o.s[3] = f2bf(v0.w);
        o.s[4] = f2bf(v1.x); o.s[5] = f2bf(v1.y);
        o.s[6] = f2bf(v1.z); o.s[7] = f2bf(v1.w);
        *(uint4*)(xbf + (size_t)row * N_ + col) = o.u;
    } else if (bx < 5248) {  // ---- weight transpose+convert ----
        const float* W; short* WT; int R, C, r0, c0, e;
        if (bx < 4224) {
            const int idx = bx - 3200;
            e = idx >> 7; const int i = idx & 127;
            W = W1; WT = W1T; R = N_; C = H_;
            r0 = (i >> 4) * 64; c0 = (i & 15) * 64;
        } else {
            const int idx = bx - 4224;
            e = idx >> 7; const int i = idx & 127;
            W = W2; WT = W2T; R = H_; C = P_;
            r0 = (i & 15) * 64; c0 = (i >> 4) * 64;
        }
        const float* Wp = W + (size_t)e * R * C;
        short* WTp = WT + (size_t)e * C * R;
        {
            const int c4 = (t & 15) * 4, r = t >> 4;
#pragma unroll
            for (int p = 0; p < 4; p++) {
                const int row = p * 16 + r;
                const float4 v = *(const float4*)(Wp + (size_t)(r0 + row) * C + c0 + c4);
                tile[row][c4 + 0] = v.x; tile[row][c4 + 1] = v.y;
                tile[row][c4 + 2] = v.z; tile[row][c4 + 3] = v.w;
            }
        }
        __syncthreads();
        {
            const int r8 = (t & 7) * 8, cl = t >> 3;
#pragma unroll
            for (int p = 0; p < 2; p++) {
                const int c = p * 32 + cl;
                union { short s[8]; uint4 u; } o;
#pragma unroll
                for (int j = 0; j < 8; j++) o.s[j] = f2bf(tile[r8 + j][c]);
                *(uint4*)(&WTp[(size_t)(c0 + c) * R + r0 + r8]) = o.u;
            }
        }
    } else {  // ---- tile-table sort (one block) ----
        if (t < E_) scnt[t] = 0;
        __syncthreads();
        int my_e = 0;
        if (t < B_) { my_e = eid[t]; atomicAdd(&scnt[my_e], 1); }
        __syncthreads();
        if (t == 0) {
            int s = 0;
            for (int i = 0; i < E_; i++) { sbase[i] = s; s += scnt[i]; }
        }
        __syncthreads();
        if (t < B_) {
            const int pos = atomicAdd(&sbase[my_e], 1);
            ttab[pos] = make_int2(t, my_e);
        }
    }
}

// 128x128 tile GEMM, one TRIAL per m-tile (rows 100..127 are staged garbage,
// computed-but-not-stored; wave-row 1 skips its all-garbage fragment via a
// wave-uniform branch with COMPILE-TIME register indices — no dynamic acc
// indexing, no spill). BK=64, 4 waves 2x2, async global_load_lds staging,
// XOR-swizzled LDS (swizzle applied on the GLOBAL address).
// FIRST:  act[(trial*100+row)][col] = softsign(xbf @ W1T^T + b1), bf16
// !FIRST: out[trial][row][col]      = act @ W2T^T + b2, fp32   (row < 100)
template <int KDIM, bool FIRST>
__global__ __launch_bounds__(256, 4) void gemm_kernel(
    const short* __restrict__ A,     // [B_*F_+pad][KDIM] bf16, K-contig
    const short* __restrict__ WT,    // [E][NCOLS][KDIM] bf16, K-contig
    const float* __restrict__ bias,  // [E][NCOLS]
    const int2* __restrict__ ttab,   // [B_] (trial, expert), expert-sorted
    short* __restrict__ actout,      // FIRST
    float* __restrict__ out)         // !FIRST
{
    constexpr int NCOLS = FIRST ? H_ : P_;
    __shared__ short sA[128 * BK];
    __shared__ short sB[128 * BK];
    const int slot = (blockIdx.x & 7) * 16 + (blockIdx.x >> 3);
    const int2 te = ttab[slot];
    const int trial = te.x, e = te.y;
    const int n0 = blockIdx.y * 128;
    const int t = threadIdx.x;
    const int lane = t & 63, w = t >> 6;
    const int wm = (w >> 1) * 64, wn = (w & 1) * 64;
    const int l15 = lane & 15, quad = lane >> 4;
    const int lr = lane >> 3;                 // staging row 0..7
    const int lc = (((lane & 7) ^ lr) * 8);   // XOR-swizzled col chunk

    f32x4 acc[4][4];
#pragma unroll
    for (int mi = 0; mi < 4; mi++)
#pragma unroll
        for (int ni = 0; ni < 4; ni++)
            acc[mi][ni] = (f32x4)(0.0f);

    const short* Ap = A + (size_t)trial * F_ * KDIM;
    const short* Bp = WT + ((size_t)e * NCOLS + n0) * KDIM;

    for (int k0 = 0; k0 < KDIM; k0 += BK) {
#pragma unroll
        for (int i = 0; i < 4; i++) {
            const int rb = w * 32 + i * 8;
            GLOAD16(Ap + (size_t)(rb + lr) * KDIM + k0 + lc, &sA[rb * BK]);
        }
#pragma unroll
        for (int i = 0; i < 4; i++) {
            const int rb = w * 32 + i * 8;
            GLOAD16(Bp + (size_t)(rb + lr) * KDIM + k0 + lc, &sB[rb * BK]);
        }
        __syncthreads();
#pragma unroll
        for (int ks = 0; ks < 2; ks++) {
            // row&7 == l15&7 for every fragment -> hoist the swizzle
            const int sw = (((ks * 4 + quad) ^ (l15 & 7)) * 8);
            bf16x8 af[4], bfr[4];
#pragma unroll
            for (int ni = 0; ni < 4; ni++)
                bfr[ni] = *(const bf16x8*)(&sB[(wn + ni * 16 + l15) * BK + sw]);
#pragma unroll
            for (int mi = 0; mi < 4; mi++) {
                if (wm + mi * 16 < F_) {  // wave-uniform; indices stay constant
                    af[mi] = *(const bf16x8*)(&sA[(wm + mi * 16 + l15) * BK + sw]);
#pragma unroll
                    for (int ni = 0; ni < 4; ni++)
                        acc[mi][ni] = __builtin_amdgcn_mfma_f32_16x16x32_bf16(af[mi], bfr[ni], acc[mi][ni], 0, 0, 0);
                }
            }
        }
        __syncthreads();
    }

    // epilogue: C/D layout col=lane&15, row=quad*4+reg
#pragma unroll
    for (int mi = 0; mi < 4; mi++) {
#pragma unroll
        for (int ni = 0; ni < 4; ni++) {
            const int col = n0 + wn + ni * 16 + l15;
            const float bv = bias[(size_t)e * NCOLS + col];
#pragma unroll
            for (int r = 0; r < 4; r++) {
                const int row = wm + mi * 16 + quad * 4 + r;  // 0..127
                if (row < F_) {
                    float v = acc[mi][ni][r] + bv;
                    if constexpr (FIRST) {
                        v = v / (1.0f + fabsf(v));  // softsign, SCALE=1
                        actout[((size_t)trial * F_ + row) * H_ + col] = f2bf(v);
                    } else {
                        out[((size_t)trial * F_ + row) * P_ + col] = v;
                    }
                }
            }
        }
    }
}

extern "C" void kernel_launch(void* const* d_in, const int* in_sizes, int n_in,
                              void* d_out, int out_size, void* d_ws, size_t ws_size,
                              hipStream_t stream) {
    const float* x  = (const float*)d_in[0];
    const int* eid  = (const int*)d_in[1];
    const float* W1 = (const float*)d_in[2];
    const float* b1 = (const float*)d_in[3];
    const float* W2 = (const float*)d_in[4];
    const float* b2 = (const float*)d_in[5];
    float* out = (float*)d_out;

    char* ws = (char*)d_ws;
    short* W1T = (short*)(ws);                          // [E][H][N]      8 MiB
    short* W2T = (short*)(ws + (size_t)(8u << 20));     // [E][P][H]      8 MiB
    short* act = (short*)(ws + (size_t)(16u << 20));    // [12800+pad][H] ~26 MiB
    short* xbf = (short*)(ws + (size_t)(43u << 20));    // [12800+pad][N] ~13 MiB
    int2* ttab = (int2*)(ws + (size_t)(57u << 20));     // [B_]

    prep<<<dim3(5249), 256, 0, stream>>>(x, W1, W2, eid, xbf, W1T, W2T, ttab);
    gemm_kernel<N_, true><<<dim3(B_, H_ / 128), 256, 0, stream>>>(xbf, W1T, b1, ttab, act, nullptr);
    gemm_kernel<H_, false><<<dim3(B_, P_ / 128), 256, 0, stream>>>(act, W2T, b2, ttab, nullptr, out);
}

// Round 7
// 154.774 us; speedup vs baseline: 4.6775x; 1.0528x over previous
//
#include <hip/hip_runtime.h>
#include <hip/hip_bf16.h>

#define B_ 128
#define F_ 100
#define N_ 512
#define H_ 1024
#define P_ 512
#define E_ 8
#define BK 64

typedef __attribute__((ext_vector_type(8))) short bf16x8;
typedef __attribute__((ext_vector_type(4))) float f32x4;

// async global->LDS DMA, 16B/lane, LDS dest = wave-uniform base + lane*16
#define GLOAD16(g, l) __builtin_amdgcn_global_load_lds(                      \
    (const __attribute__((address_space(1))) void*)(g),                      \
    (__attribute__((address_space(3))) void*)(l), 16, 0, 0)

static __device__ __forceinline__ short f2bf(float f) {
    __hip_bfloat16 h = __float2bfloat16(f);
    short s;
    __builtin_memcpy(&s, &h, sizeof(s));
    return s;
}

// ONE prep kernel, grid sections:
//   [0,3200)      convert x [B][F][N] fp32 -> xbf [12800][N] bf16 (linear)
//   [3200,4224)   transpose W1 [E][512][1024] -> W1T [E][1024][512] bf16
//   [4224,5248)   transpose W2 [E][1024][512] -> W2T [E][512][1024] bf16
//   5248          tile table sorted by expert (data stays in trial order):
//                 ttab[slot]=(trial,eid); GEMM slot s -> XCD s%8-grouped so
//                 each XCD sees 16 expert-contiguous trials (1-2 experts).
__global__ __launch_bounds__(256) void prep(
    const float* __restrict__ x, const float* __restrict__ W1,
    const float* __restrict__ W2, const int* __restrict__ eid,
    short* __restrict__ xbf, short* __restrict__ W1T, short* __restrict__ W2T,
    int2* __restrict__ ttab) {
    __shared__ float tile[64][65];
    __shared__ int scnt[E_], sbase[E_];
    const int bx = blockIdx.x;
    const int t = threadIdx.x;
    if (bx < 3200) {  // ---- convert x ----
        const int g = bx * 256 + t;
        const int col = (g & 63) * 8;
        const int row = g >> 6;  // 0..12799
        const float* xp = x + (size_t)row * N_ + col;
        const float4 v0 = *(const float4*)(xp);
        const float4 v1 = *(const float4*)(xp + 4);
        union { short s[8]; uint4 u; } o;
        o.s[0] = f2bf(v0.x); o.s[1] = f2bf(v0.y);
        o.s[2] = f2bf(v0.z); o.s[3] = f2bf(v0.w);
        o.s[4] = f2bf(v1.x); o.s[5] = f2bf(v1.y);
        o.s[6] = f2bf(v1.z); o.s[7] = f2bf(v1.w);
        *(uint4*)(xbf + (size_t)row * N_ + col) = o.u;
    } else if (bx < 5248) {  // ---- weight transpose+convert ----
        const float* W; short* WT; int R, C, r0, c0, e;
        if (bx < 4224) {
            const int idx = bx - 3200;
            e = idx >> 7; const int i = idx & 127;
            W = W1; WT = W1T; R = N_; C = H_;
            r0 = (i >> 4) * 64; c0 = (i & 15) * 64;
        } else {
            const int idx = bx - 4224;
            e = idx >> 7; const int i = idx & 127;
            W = W2; WT = W2T; R = H_; C = P_;
            r0 = (i & 15) * 64; c0 = (i >> 4) * 64;
        }
        const float* Wp = W + (size_t)e * R * C;
        short* WTp = WT + (size_t)e * C * R;
        {
            const int c4 = (t & 15) * 4, r = t >> 4;
#pragma unroll
            for (int p = 0; p < 4; p++) {
                const int row = p * 16 + r;
                const float4 v = *(const float4*)(Wp + (size_t)(r0 + row) * C + c0 + c4);
                tile[row][c4 + 0] = v.x; tile[row][c4 + 1] = v.y;
                tile[row][c4 + 2] = v.z; tile[row][c4 + 3] = v.w;
            }
        }
        __syncthreads();
        {
            const int r8 = (t & 7) * 8, cl = t >> 3;
#pragma unroll
            for (int p = 0; p < 2; p++) {
                const int c = p * 32 + cl;
                union { short s[8]; uint4 u; } o;
#pragma unroll
                for (int j = 0; j < 8; j++) o.s[j] = f2bf(tile[r8 + j][c]);
                *(uint4*)(&WTp[(size_t)(c0 + c) * R + r0 + r8]) = o.u;
            }
        }
    } else {  // ---- tile-table sort (one block) ----
        if (t < E_) scnt[t] = 0;
        __syncthreads();
        int my_e = 0;
        if (t < B_) { my_e = eid[t]; atomicAdd(&scnt[my_e], 1); }
        __syncthreads();
        if (t == 0) {
            int s = 0;
            for (int i = 0; i < E_; i++) { sbase[i] = s; s += scnt[i]; }
        }
        __syncthreads();
        if (t < B_) {
            const int pos = atomicAdd(&sbase[my_e], 1);
            ttab[pos] = make_int2(t, my_e);
        }
    }
}

// 128x128 tile GEMM, one TRIAL per m-tile (rows 100..127 staged garbage,
// wave-row 1 skips its all-garbage m-frag via wave-uniform branch with
// compile-time register indices). BK=64, 4 waves 2x2, async global_load_lds
// staging, XOR-swizzled LDS. Epilogue: acc -> per-wave LDS region (reusing
// the staging buffer after the final barrier, XOR-chunk swizzle) -> re-read
// row-major -> 16B coalesced global stores (8-16 vector stores/thread
// instead of 64 scalar ones).
// FIRST:  act[(trial*100+row)][col] = softsign(xbf @ W1T^T + b1), bf16
// !FIRST: out[trial][row][col]      = act @ W2T^T + b2, fp32   (row < 100)
template <int KDIM, bool FIRST>
__global__ __launch_bounds__(256, 4) void gemm_kernel(
    const short* __restrict__ A,     // [B_*F_+128pad][KDIM] bf16, K-contig
    const short* __restrict__ WT,    // [E][NCOLS][KDIM] bf16, K-contig
    const float* __restrict__ bias,  // [E][NCOLS]
    const int2* __restrict__ ttab,   // [B_] (trial, expert), expert-sorted
    short* __restrict__ actout,      // FIRST
    float* __restrict__ out)         // !FIRST
{
    constexpr int NCOLS = FIRST ? H_ : P_;
    __shared__ short sbuf[2 * 128 * BK];   // 32 KiB: staging, then epilogue
    short* sA = sbuf;
    short* sB = sbuf + 128 * BK;
    const int slot = (blockIdx.x & 7) * 16 + (blockIdx.x >> 3);
    const int2 te = ttab[slot];
    const int trial = te.x, e = te.y;
    const int n0 = blockIdx.y * 128;
    const int t = threadIdx.x;
    const int lane = t & 63, w = t >> 6;
    const int wm = (w >> 1) * 64, wn = (w & 1) * 64;
    const int l15 = lane & 15, quad = lane >> 4;
    const int lr = lane >> 3;                 // staging row 0..7
    const int lc = (((lane & 7) ^ lr) * 8);   // XOR-swizzled col chunk

    f32x4 acc[4][4];
#pragma unroll
    for (int mi = 0; mi < 4; mi++)
#pragma unroll
        for (int ni = 0; ni < 4; ni++)
            acc[mi][ni] = (f32x4)(0.0f);

    const short* Ap = A + (size_t)trial * F_ * KDIM;
    const short* Bp = WT + ((size_t)e * NCOLS + n0) * KDIM;

    for (int k0 = 0; k0 < KDIM; k0 += BK) {
#pragma unroll
        for (int i = 0; i < 4; i++) {
            const int rb = w * 32 + i * 8;
            GLOAD16(Ap + (size_t)(rb + lr) * KDIM + k0 + lc, &sA[rb * BK]);
        }
#pragma unroll
        for (int i = 0; i < 4; i++) {
            const int rb = w * 32 + i * 8;
            GLOAD16(Bp + (size_t)(rb + lr) * KDIM + k0 + lc, &sB[rb * BK]);
        }
        __syncthreads();
#pragma unroll
        for (int ks = 0; ks < 2; ks++) {
            const int sw = (((ks * 4 + quad) ^ (l15 & 7)) * 8);
            bf16x8 af[4], bfr[4];
#pragma unroll
            for (int ni = 0; ni < 4; ni++)
                bfr[ni] = *(const bf16x8*)(&sB[(wn + ni * 16 + l15) * BK + sw]);
#pragma unroll
            for (int mi = 0; mi < 4; mi++) {
                if (wm + mi * 16 < F_) {  // wave-uniform; indices constant
                    af[mi] = *(const bf16x8*)(&sA[(wm + mi * 16 + l15) * BK + sw]);
#pragma unroll
                    for (int ni = 0; ni < 4; ni++)
                        acc[mi][ni] = __builtin_amdgcn_mfma_f32_16x16x32_bf16(af[mi], bfr[ni], acc[mi][ni], 0, 0, 0);
                }
            }
        }
        __syncthreads();  // also protects sbuf reuse by the epilogue
    }

    // ---- epilogue via per-wave LDS transpose -> coalesced 16B stores ----
    // C/D frag layout: col=lane&15, row=quad*4+reg.
    if constexpr (FIRST) {
        short* sW = sbuf + w * 4096;  // 64 rows x 64 bf16, chunk^=(row&7)
#pragma unroll
        for (int mi = 0; mi < 4; mi++) {
#pragma unroll
            for (int ni = 0; ni < 4; ni++) {
                const int cl = ni * 16 + l15;
                const float bv = bias[(size_t)e * NCOLS + n0 + wn + cl];
#pragma unroll
                for (int r = 0; r < 4; r++) {
                    const int rl = mi * 16 + quad * 4 + r;  // 0..63
                    float v = acc[mi][ni][r] + bv;
                    v = v / (1.0f + fabsf(v));  // softsign, SCALE=1
                    sW[rl * 64 + (((cl >> 3) ^ (rl & 7)) * 8) + (cl & 7)] = f2bf(v);
                }
            }
        }
#pragma unroll
        for (int i = 0; i < 8; i++) {
            const int rl = i * 8 + lr;        // 0..63 (rl&7 == lr)
            const int c = lane & 7;
            const bf16x8 v = *(const bf16x8*)(&sW[rl * 64 + ((c ^ lr) * 8)]);
            const int grow = wm + rl;
            if (grow < F_)
                *(bf16x8*)(&actout[((size_t)trial * F_ + grow) * H_ + n0 + wn + c * 8]) = v;
        }
    } else {
        float* fW = (float*)(sbuf) + w * 2048;  // 32 rows x 64 fp32 per pass
#pragma unroll
        for (int half = 0; half < 2; half++) {
#pragma unroll
            for (int mi2 = 0; mi2 < 2; mi2++) {
                const int mi = half * 2 + mi2;
#pragma unroll
                for (int ni = 0; ni < 4; ni++) {
                    const int cl = ni * 16 + l15;
                    const float bv = bias[(size_t)e * NCOLS + n0 + wn + cl];
#pragma unroll
                    for (int r = 0; r < 4; r++) {
                        const int rl = mi2 * 16 + quad * 4 + r;  // 0..31
                        fW[rl * 64 + (((cl >> 2) ^ (rl & 7)) * 4) + (cl & 3)] =
                            acc[mi][ni][r] + bv;
                    }
                }
            }
#pragma unroll
            for (int i = 0; i < 8; i++) {
                const int rl = i * 4 + (lane >> 4);  // 0..31
                const int c = lane & 15;             // 16B chunk index
                const float4 v = *(const float4*)(&fW[rl * 64 + ((c ^ (rl & 7)) * 4)]);
                const int grow = wm + half * 32 + rl;
                if (grow < F_)
                    *(float4*)(&out[((size_t)trial * F_ + grow) * P_ + n0 + wn + c * 4]) = v;
            }
            // per-wave private region; next pass overwrites after reads —
            // wave-internal lgkmcnt ordering handles the dependency
        }
    }
}

extern "C" void kernel_launch(void* const* d_in, const int* in_sizes, int n_in,
                              void* d_out, int out_size, void* d_ws, size_t ws_size,
                              hipStream_t stream) {
    const float* x  = (const float*)d_in[0];
    const int* eid  = (const int*)d_in[1];
    const float* W1 = (const float*)d_in[2];
    const float* b1 = (const float*)d_in[3];
    const float* W2 = (const float*)d_in[4];
    const float* b2 = (const float*)d_in[5];
    float* out = (float*)d_out;

    char* ws = (char*)d_ws;
    short* W1T = (short*)(ws);                          // [E][H][N]      8 MiB
    short* W2T = (short*)(ws + (size_t)(8u << 20));     // [E][P][H]      8 MiB
    short* act = (short*)(ws + (size_t)(16u << 20));    // [12800+128][H] ~26.5 MiB
    short* xbf = (short*)(ws + (size_t)(43u << 20));    // [12800+128][N] ~13.3 MiB
    int2* ttab = (int2*)(ws + (size_t)(57u << 20));     // [B_]

    prep<<<dim3(5249), 256, 0, stream>>>(x, W1, W2, eid, xbf, W1T, W2T, ttab);
    gemm_kernel<N_, true><<<dim3(B_, H_ / 128), 256, 0, stream>>>(xbf, W1T, b1, ttab, act, nullptr);
    gemm_kernel<H_, false><<<dim3(B_, P_ / 128), 256, 0, stream>>>(act, W2T, b2, ttab, nullptr, out);
}

// Round 9
// 153.328 us; speedup vs baseline: 4.7216x; 1.0094x over previous
//
#include <hip/hip_runtime.h>
#include <hip/hip_bf16.h>

#define B_ 128
#define F_ 100
#define N_ 512
#define H_ 1024
#define P_ 512
#define E_ 8
#define BK 64

typedef __attribute__((ext_vector_type(8))) short bf16x8;
typedef __attribute__((ext_vector_type(4))) float f32x4;

// async global->LDS DMA, 16B/lane, LDS dest = wave-uniform base + lane*16
#define GLOAD16(g, l) __builtin_amdgcn_global_load_lds(                      \
    (const __attribute__((address_space(1))) void*)(g),                      \
    (__attribute__((address_space(3))) void*)(l), 16, 0, 0)

static __device__ __forceinline__ short f2bf(float f) {
    __hip_bfloat16 h = __float2bfloat16(f);
    short s;
    __builtin_memcpy(&s, &h, sizeof(s));
    return s;
}

// ONE prep kernel, grid sections:
//   [0,3200)      convert x [B][F][N] fp32 -> xbf [12800][N] bf16 (linear)
//   [3200,4224)   transpose W1 [E][512][1024] -> W1T [E][1024][512] bf16
//   [4224,5248)   transpose W2 [E][1024][512] -> W2T [E][512][1024] bf16
//   5248          tile table sorted by expert (data stays in trial order):
//                 ttab[slot]=(trial,eid); GEMM slot s -> XCD s%8-grouped so
//                 each XCD sees 16 expert-contiguous trials (1-2 experts).
__global__ __launch_bounds__(256) void prep(
    const float* __restrict__ x, const float* __restrict__ W1,
    const float* __restrict__ W2, const int* __restrict__ eid,
    short* __restrict__ xbf, short* __restrict__ W1T, short* __restrict__ W2T,
    int2* __restrict__ ttab) {
    __shared__ float tile[64][65];
    __shared__ int scnt[E_], sbase[E_];
    const int bx = blockIdx.x;
    const int t = threadIdx.x;
    if (bx < 3200) {  // ---- convert x ----
        const int g = bx * 256 + t;
        const int col = (g & 63) * 8;
        const int row = g >> 6;  // 0..12799
        const float* xp = x + (size_t)row * N_ + col;
        const float4 v0 = *(const float4*)(xp);
        const float4 v1 = *(const float4*)(xp + 4);
        union { short s[8]; uint4 u; } o;
        o.s[0] = f2bf(v0.x); o.s[1] = f2bf(v0.y);
        o.s[2] = f2bf(v0.z); o.s[3] = f2bf(v0.w);
        o.s[4] = f2bf(v1.x); o.s[5] = f2bf(v1.y);
        o.s[6] = f2bf(v1.z); o.s[7] = f2bf(v1.w);
        *(uint4*)(xbf + (size_t)row * N_ + col) = o.u;
    } else if (bx < 5248) {  // ---- weight transpose+convert ----
        const float* W; short* WT; int R, C, r0, c0, e;
        if (bx < 4224) {
            const int idx = bx - 3200;
            e = idx >> 7; const int i = idx & 127;
            W = W1; WT = W1T; R = N_; C = H_;
            r0 = (i >> 4) * 64; c0 = (i & 15) * 64;
        } else {
            const int idx = bx - 4224;
            e = idx >> 7; const int i = idx & 127;
            W = W2; WT = W2T; R = H_; C = P_;
            r0 = (i & 15) * 64; c0 = (i >> 4) * 64;
        }
        const float* Wp = W + (size_t)e * R * C;
        short* WTp = WT + (size_t)e * C * R;
        {
            const int c4 = (t & 15) * 4, r = t >> 4;
#pragma unroll
            for (int p = 0; p < 4; p++) {
                const int row = p * 16 + r;
                const float4 v = *(const float4*)(Wp + (size_t)(r0 + row) * C + c0 + c4);
                tile[row][c4 + 0] = v.x; tile[row][c4 + 1] = v.y;
                tile[row][c4 + 2] = v.z; tile[row][c4 + 3] = v.w;
            }
        }
        __syncthreads();
        {
            const int r8 = (t & 7) * 8, cl = t >> 3;
#pragma unroll
            for (int p = 0; p < 2; p++) {
                const int c = p * 32 + cl;
                union { short s[8]; uint4 u; } o;
#pragma unroll
                for (int j = 0; j < 8; j++) o.s[j] = f2bf(tile[r8 + j][c]);
                *(uint4*)(&WTp[(size_t)(c0 + c) * R + r0 + r8]) = o.u;
            }
        }
    } else {  // ---- tile-table sort (one block) ----
        if (t < E_) scnt[t] = 0;
        __syncthreads();
        int my_e = 0;
        if (t < B_) { my_e = eid[t]; atomicAdd(&scnt[my_e], 1); }
        __syncthreads();
        if (t == 0) {
            int s = 0;
            for (int i = 0; i < E_; i++) { sbase[i] = s; s += scnt[i]; }
        }
        __syncthreads();
        if (t < B_) {
            const int pos = atomicAdd(&sbase[my_e], 1);
            ttab[pos] = make_int2(t, my_e);
        }
    }
}

// 128xBN_ tile GEMM, one TRIAL per m-tile. A staged rows 0..111 only (14 DMA;
// rows 112..127 of sA never read). Wave-row 1 skips its all-garbage m-frag
// via wave-uniform branch with compile-time register indices. BK=64, 4 waves
// 2x2, async global_load_lds staging, XOR-swizzled LDS (swizzle on the
// GLOBAL address). Epilogue: acc -> per-wave LDS -> 16B coalesced stores.
// LDS sized max(staging, 4-wave epilogue) = 32 KiB (R8 bug: BN=64 staging
// was 24 KiB but epilogue needs 32 KiB -> OOB LDS writes).
// FIRST:  act[(trial*100+row)][col] = softsign(xbf @ W1T^T + b1), bf16
// !FIRST: out[trial][row][col]      = act @ W2T^T + b2, fp32   (row < 100)
template <int KDIM, int BN_, bool FIRST>
__global__ __launch_bounds__(256, 4) void gemm_kernel(
    const short* __restrict__ A,     // [B_*F_+128pad][KDIM] bf16, K-contig
    const short* __restrict__ WT,    // [E][NCOLS][KDIM] bf16, K-contig
    const float* __restrict__ bias,  // [E][NCOLS]
    const int2* __restrict__ ttab,   // [B_] (trial, expert), expert-sorted
    short* __restrict__ actout,      // FIRST
    float* __restrict__ out)         // !FIRST
{
    constexpr int NCOLS = FIRST ? H_ : P_;
    constexpr int NI = BN_ / 32;            // n-frags per wave
    constexpr int STAGE_SH = 128 * BK + BN_ * BK;   // staging shorts
    constexpr int EPI_SH = 4 * 4096;                // 4 waves x 8 KiB
    constexpr int SBUF_SH = STAGE_SH > EPI_SH ? STAGE_SH : EPI_SH;
    __shared__ short sbuf[SBUF_SH];
    short* sA = sbuf;
    short* sB = sbuf + 128 * BK;
    const int slot = (blockIdx.x & 7) * 16 + (blockIdx.x >> 3);
    const int2 te = ttab[slot];
    const int trial = te.x, e = te.y;
    const int n0 = blockIdx.y * BN_;
    const int t = threadIdx.x;
    const int lane = t & 63, w = t >> 6;
    const int wm = (w >> 1) * 64, wn = (w & 1) * (BN_ / 2);
    const int l15 = lane & 15, quad = lane >> 4;
    const int lr = lane >> 3;                 // staging row 0..7
    const int lc = (((lane & 7) ^ lr) * 8);   // XOR-swizzled col chunk

    f32x4 acc[4][NI];
#pragma unroll
    for (int mi = 0; mi < 4; mi++)
#pragma unroll
        for (int ni = 0; ni < NI; ni++)
            acc[mi][ni] = (f32x4)(0.0f);

    // hoist bias (depends on ni only)
    float bv[NI];
#pragma unroll
    for (int ni = 0; ni < NI; ni++)
        bv[ni] = bias[(size_t)e * NCOLS + n0 + wn + ni * 16 + l15];

    const short* Ap = A + (size_t)trial * F_ * KDIM;
    const short* Bp = WT + ((size_t)e * NCOLS + n0) * KDIM;

    for (int k0 = 0; k0 < KDIM; k0 += BK) {
#pragma unroll
        for (int i = 0; i < 4; i++) {
            const int rb = w * 32 + i * 8;
            if (rb < 112)  // wave-uniform; rows 112..127 never read
                GLOAD16(Ap + (size_t)(rb + lr) * KDIM + k0 + lc, &sA[rb * BK]);
        }
#pragma unroll
        for (int i = 0; i < NI; i++) {
            const int rb = w * (BN_ / 4) + i * 8;
            GLOAD16(Bp + (size_t)(rb + lr) * KDIM + k0 + lc, &sB[rb * BK]);
        }
        __syncthreads();
#pragma unroll
        for (int ks = 0; ks < 2; ks++) {
            const int sw = (((ks * 4 + quad) ^ (l15 & 7)) * 8);
            bf16x8 af[4], bfr[NI];
#pragma unroll
            for (int ni = 0; ni < NI; ni++)
                bfr[ni] = *(const bf16x8*)(&sB[(wn + ni * 16 + l15) * BK + sw]);
#pragma unroll
            for (int mi = 0; mi < 4; mi++) {
                if (wm + mi * 16 < F_) {  // wave-uniform; indices constant
                    af[mi] = *(const bf16x8*)(&sA[(wm + mi * 16 + l15) * BK + sw]);
#pragma unroll
                    for (int ni = 0; ni < NI; ni++)
                        acc[mi][ni] = __builtin_amdgcn_mfma_f32_16x16x32_bf16(af[mi], bfr[ni], acc[mi][ni], 0, 0, 0);
                }
            }
        }
        __syncthreads();  // also protects sbuf reuse by the epilogue
    }

    // ---- epilogue via per-wave LDS transpose -> coalesced 16B stores ----
    // C/D frag layout: col=lane&15, row=quad*4+reg.
    if constexpr (FIRST) {
        short* sW = sbuf + w * 4096;  // 64 rows x 64 bf16, chunk^=(row&7)
#pragma unroll
        for (int mi = 0; mi < 4; mi++) {
#pragma unroll
            for (int ni = 0; ni < 4; ni++) {
                const int cl = ni * 16 + l15;
#pragma unroll
                for (int r = 0; r < 4; r++) {
                    const int rl = mi * 16 + quad * 4 + r;  // 0..63
                    float v = acc[mi][ni][r] + bv[ni];
                    v = v / (1.0f + fabsf(v));  // softsign, SCALE=1
                    sW[rl * 64 + (((cl >> 3) ^ (rl & 7)) * 8) + (cl & 7)] = f2bf(v);
                }
            }
        }
#pragma unroll
        for (int i = 0; i < 8; i++) {
            const int rl = i * 8 + lr;        // 0..63 (rl&7 == lr)
            const int c = lane & 7;
            const bf16x8 v = *(const bf16x8*)(&sW[rl * 64 + ((c ^ lr) * 8)]);
            const int grow = wm + rl;
            if (grow < F_)
                *(bf16x8*)(&actout[((size_t)trial * F_ + grow) * H_ + n0 + wn + c * 8]) = v;
        }
    } else {
        float* fW = (float*)(sbuf) + w * 2048;  // 64 rows x 32 fp32 per wave
#pragma unroll
        for (int mi = 0; mi < 4; mi++) {
#pragma unroll
            for (int ni = 0; ni < NI; ni++) {
                const int cl = ni * 16 + l15;   // 0..31
#pragma unroll
                for (int r = 0; r < 4; r++) {
                    const int rl = mi * 16 + quad * 4 + r;  // 0..63
                    fW[rl * 32 + (((cl >> 2) ^ (rl & 7)) * 4) + (cl & 3)] =
                        acc[mi][ni][r] + bv[ni];
                }
            }
        }
#pragma unroll
        for (int i = 0; i < 8; i++) {
            const int rl = i * 8 + lr;           // 0..63 (rl&7 == lr)
            const int c = lane & 7;              // 16B chunk, 32 cols = 8 chunks
            const float4 v = *(const float4*)(&fW[rl * 32 + ((c ^ lr) * 4)]);
            const int grow = wm + rl;
            if (grow < F_)
                *(float4*)(&out[((size_t)trial * F_ + grow) * P_ + n0 + wn + c * 4]) = v;
        }
    }
}

extern "C" void kernel_launch(void* const* d_in, const int* in_sizes, int n_in,
                              void* d_out, int out_size, void* d_ws, size_t ws_size,
                              hipStream_t stream) {
    const float* x  = (const float*)d_in[0];
    const int* eid  = (const int*)d_in[1];
    const float* W1 = (const float*)d_in[2];
    const float* b1 = (const float*)d_in[3];
    const float* W2 = (const float*)d_in[4];
    const float* b2 = (const float*)d_in[5];
    float* out = (float*)d_out;

    char* ws = (char*)d_ws;
    short* W1T = (short*)(ws);                          // [E][H][N]      8 MiB
    short* W2T = (short*)(ws + (size_t)(8u << 20));     // [E][P][H]      8 MiB
    short* act = (short*)(ws + (size_t)(16u << 20));    // [12800+128][H] ~26.5 MiB
    short* xbf = (short*)(ws + (size_t)(43u << 20));    // [12800+128][N] ~13.3 MiB
    int2* ttab = (int2*)(ws + (size_t)(57u << 20));     // [B_]

    prep<<<dim3(5249), 256, 0, stream>>>(x, W1, W2, eid, xbf, W1T, W2T, ttab);
    gemm_kernel<N_, 128, true><<<dim3(B_, H_ / 128), 256, 0, stream>>>(xbf, W1T, b1, ttab, act, nullptr);
    gemm_kernel<H_, 64, false><<<dim3(B_, P_ / 64), 256, 0, stream>>>(act, W2T, b2, ttab, nullptr, out);
}